// Round 1
// baseline (180.215 us; speedup 1.0000x reference)
//
#include <hip/hip_runtime.h>
#include <hip/hip_bf16.h>
#include <math.h>

#define DI __device__ __forceinline__

typedef __bf16 bf16x8 __attribute__((ext_vector_type(8)));
typedef float  f32x4  __attribute__((ext_vector_type(4)));

static constexpr int   Bsz  = 2, Ssz = 4096, Hsz = 2048, Dsz = 128;
static constexpr int   Nrow = Bsz * Ssz;     // 8192
static constexpr int   NCH  = Nrow / 128;    // 64 chunks
static constexpr int   CPB  = Ssz / 128;     // 32 chunks per batch
static constexpr int   WN   = Dsz * Hsz;     // 262144
static constexpr float EPSF = 1e-6f;

// ---------------- workspace layout (bytes) ----------------
static constexpr size_t WQKV_OFF = 0;                            // bf16 [384][2048]
static constexpr size_t WO_OFF   = (size_t)3*WN*2;               // bf16 [2048][128]
static constexpr size_t MB_OFF   = WO_OFF + (size_t)WN*2;        // bf16 [128][128] (cvt spill)
static constexpr size_t MBT_OFF  = MB_OFF + 32768;               // bf16 M^T [128][128]
static constexpr size_t QB_OFF   = MBT_OFF + 32768;              // bf16 [8192][128]
static constexpr size_t KB_OFF   = QB_OFF + (size_t)Nrow*Dsz*2;
static constexpr size_t VB_OFF   = KB_OFF + (size_t)Nrow*Dsz*2;
static constexpr size_t PB_OFF   = VB_OFF + (size_t)Nrow*Dsz*2;
static constexpr size_t ACC_OFF  = PB_OFF + (size_t)Nrow*Dsz*2;  // bf16 [4][3][8192][128] = 25.2MB
// --- aliased into ACC region (dead after k_qkv_epi) ---
static constexpr size_t KV_OFF   = ACC_OFF;                      // f32 [64][128d][128e] 4MB
static constexpr size_t KVP_OFF  = ACC_OFF + (size_t)4*1024*1024;// bf16 [64][128d][128e] 2MB
static constexpr size_t MPART_OFF= ACC_OFF + (size_t)6*1024*1024;// f32 [64][128][128] 4MB
static constexpr size_t KSUM_OFF = ACC_OFF + (size_t)10*1024*1024;// f32 [64][128]
static constexpr size_t KPRE_OFF = KSUM_OFF + 32768;             // f32 [64][128]

// ---------------- helpers ----------------
DI float b2f(unsigned short u) {
    union { float f; unsigned int i; } x; x.i = ((unsigned int)u) << 16; return x.f;
}
DI unsigned short f2b(float f) {
    __bf16 h = (__bf16)f; return __builtin_bit_cast(unsigned short, h);
}
DI float sig_elu(float x) { return x > 0.f ? x + 1.f : expf(x); }

DI f32x4 MFMA(bf16x8 a, bf16x8 b, f32x4 c) {
    return __builtin_amdgcn_mfma_f32_16x16x32_bf16(a, b, c, 0, 0, 0);
}
template<int NB>
DI void zaccg(f32x4 (&acc)[4][NB]) {
    f32x4 zz = {0.f, 0.f, 0.f, 0.f};
    #pragma unroll
    for (int i = 0; i < 4; i++)
        #pragma unroll
        for (int j = 0; j < NB; j++) acc[i][j] = zz;
}

// async 16B global -> LDS (DMA, bypasses VGPRs). LDS dst = wave-uniform base + lane*16.
DI void gll16(const void* g, void* l) {
    __builtin_amdgcn_global_load_lds((const __attribute__((address_space(1))) void*)g,
                                     (__attribute__((address_space(3))) void*)l, 16, 0, 0);
}

// swizzled chunk offset (ushorts) of 8-elem chunk (r, kc) in a VALU-staged operand
// tile with R rows (XOR banking)
DI int swzR(int r, int kc, int R) { return (kc*R + (r ^ (kc & 7))) * 8; }

// generic matmul out of swzR-layout LDS: A 128 rows, B NB*32 rows
template<int NKS, int NB>
DI void mmg(const unsigned short* A, const unsigned short* Bm, f32x4 (&acc)[4][NB],
            int wm, int wn, int quad, int lr) {
    #pragma unroll
    for (int ks = 0; ks < NKS; ks++) {
        bf16x8 a[4], b[NB];
        #pragma unroll
        for (int mb = 0; mb < 4; mb++)
            a[mb] = *(const bf16x8*)&A[swzR(wm*64 + mb*16 + lr, ks*4 + quad, 128)];
        #pragma unroll
        for (int nb = 0; nb < NB; nb++)
            b[nb] = *(const bf16x8*)&Bm[swzR(wn*(NB*16) + nb*16 + lr, ks*4 + quad, NB*32)];
        #pragma unroll
        for (int mb = 0; mb < 4; mb++)
            #pragma unroll
            for (int nb = 0; nb < NB; nb++)
                acc[mb][nb] = MFMA(a[mb], b[nb], acc[mb][nb]);
    }
}

// row-major [R][128] bf16 tile -> swzR operand layout (VALU path)
template<int R>
DI void stage_dir(unsigned short* dst, const unsigned short* src, int src_ld, int tid) {
    #pragma unroll
    for (int i = 0; i < R/16; i++) {
        int s = tid + i*256; int r = s >> 4, kc = s & 15;
        *(uint4*)&dst[swzR(r, kc, R)] = *(const uint4*)(src + (size_t)r*src_ld + kc*8);
    }
}

// transposed staging (full 128): operand elem (r=col, k=row) <- src[row][col]
DI void stage_T128(unsigned short* dst, const unsigned short* src, int src_ld, int tid) {
    #pragma unroll
    for (int i = 0; i < 8; i++) {
        int s = tid + i*256;
        int rw = (s & 15) + ((s >> 8) << 4);
        int c0 = ((s >> 4) & 15) * 8;
        unsigned short tmp[8];
        *(uint4*)tmp = *(const uint4*)(src + (size_t)rw*src_ld + c0);
        #pragma unroll
        for (int j = 0; j < 8; j++)
            dst[swzR(c0 + j, rw >> 3, 128) + (rw & 7)] = tmp[j];
    }
}

// transposed staging into 32-row operand: elem (r=col-colOff, k=row) <- src[row][colOff+col]
DI void stage_T32(unsigned short* dst, const unsigned short* src, int src_ld, int colOff, int tid) {
    #pragma unroll
    for (int i = 0; i < 2; i++) {
        int s = tid + i*256;                     // 0..511
        int rw = (s & 15) + ((s >> 6) << 4);     // 0..127
        int c0 = ((s >> 4) & 3) * 8;             // 0..24
        unsigned short tmp[8];
        *(uint4*)tmp = *(const uint4*)(src + (size_t)rw*src_ld + colOff + c0);
        #pragma unroll
        for (int j = 0; j < 8; j++)
            dst[swzR(c0 + j, rw >> 3, 32) + (rw & 7)] = tmp[j];
    }
}

// ---------------- kernels ----------------

// fused weight conversion: wq|wk|wv -> Wqkv, wo -> Wo, M -> (spill) and MbT
__global__ void k_cvt_w(const float* __restrict__ wq, const float* __restrict__ wk,
                        const float* __restrict__ wv, const float* __restrict__ wo,
                        const float* __restrict__ M, unsigned short* __restrict__ dst,
                        unsigned short* __restrict__ MbT)
{
    int gid = blockIdx.x*256 + threadIdx.x;
    if (gid >= (4*WN + 16384)/4) return;
    int e = gid*4;
    const float* src; int rel;
    if      (e < WN)     { src = wq; rel = e; }
    else if (e < 2*WN)   { src = wk; rel = e - WN; }
    else if (e < 3*WN)   { src = wv; rel = e - 2*WN; }
    else if (e < 4*WN)   { src = wo; rel = e - 3*WN; }
    else                 { src = M;  rel = e - 4*WN; }
    float4 v = *(const float4*)(src + rel);
    const float* vf = (const float*)&v;
    unsigned short o[4];
    #pragma unroll
    for (int j = 0; j < 4; j++) o[j] = f2b(vf[j]);
    *(uint2*)&dst[e] = *(const uint2*)o;
    if (e >= 4*WN) {
        #pragma unroll
        for (int j = 0; j < 4; j++) {
            int d = (rel + j) >> 7, ee = (rel + j) & 127;
            MbT[ee*128 + d] = o[j];
        }
    }
}

// QKV projection v2, single X pass: X[8192,2048]fp32 @ Wqkv[384,2048]^T
// One 512-thread block computes the full 128x384 (Q|K|V) tile for its
// (row-block, K-split). X read ONCE (was 3x). A converted to bf16 during
// staging (reg path, once per element); B (all 384 W rows) via global_load_lds.
// Inner loop is pure ds_read_b128 + MFMA (no v_cvt).
__global__ __launch_bounds__(512, 2) void k_gemm_qkv(
    const float* __restrict__ X, const unsigned short* __restrict__ W,
    unsigned short* __restrict__ AccB)
{
    __shared__ unsigned short lA[128*64];   // bf16, chunk slot p = r*8 + (kc^(r&7))   16KB
    __shared__ unsigned short lB[384*64];   // bf16, chunk slot p = r*8 + (kc^(r&7))   48KB
    const int tid = threadIdx.x;            // 0..511
    const int row0 = blockIdx.x * 128;
    const int kb   = blockIdx.y * 512;      // K-split of 4
    const int wave = tid >> 6, lane = tid & 63;
    const int wm = wave >> 2, wn = wave & 3;      // wm 0..1 (64 rows), wn 0..3 (96 cols)
    const int quad = lane >> 4, lr = lane & 15;

    // per-thread A staging geometry: 1024 chunks of 8 fp32 -> 2 chunks/thread
    const int cA0 = tid, cA1 = tid + 512;
    const int rA0 = cA0 >> 3, kA0 = cA0 & 7;
    const int rA1 = cA1 >> 3, kA1 = cA1 & 7;
    const float* pA0 = X + (size_t)(row0 + rA0)*Hsz + kA0*8;
    const float* pA1 = X + (size_t)(row0 + rA1)*Hsz + kA1*8;
    unsigned short* wA0 = &lA[(rA0*8 + (kA0 ^ (rA0 & 7)))*8];
    unsigned short* wA1 = &lA[(rA1*8 + (kA1 ^ (rA1 & 7)))*8];

    f32x4 acc[4][6];
    {
        f32x4 zz = {0.f, 0.f, 0.f, 0.f};
        #pragma unroll
        for (int i = 0; i < 4; i++)
            #pragma unroll
            for (int j = 0; j < 6; j++) acc[i][j] = zz;
    }

    // prologue: issue A register loads for first K-step
    float4 a00 = *(const float4*)(pA0 + kb);
    float4 a01 = *(const float4*)(pA0 + kb + 4);
    float4 a10 = *(const float4*)(pA1 + kb);
    float4 a11 = *(const float4*)(pA1 + kb + 4);

    for (int kt = kb; kt < kb + 512; kt += 64) {
        // B: 3072 chunks of 8 bf16 -> 6 DMA/thread (source XOR-permuted)
        #pragma unroll
        for (int i = 0; i < 6; i++) {
            int p = tid + i*512; int r = p >> 3; int kc = (p & 7) ^ (r & 7);
            gll16(W + (size_t)r*Hsz + kt + kc*8, &lB[p*8]);
        }
        // A: cvt staged regs -> bf16 swizzled LDS (waits A loads, B DMA stays in flight)
        {
            unsigned short o[8];
            const float* f0 = (const float*)&a00; const float* f1 = (const float*)&a01;
            #pragma unroll
            for (int j = 0; j < 4; j++) { o[j] = f2b(f0[j]); o[4+j] = f2b(f1[j]); }
            *(uint4*)wA0 = *(const uint4*)o;
            const float* f2 = (const float*)&a10; const float* f3 = (const float*)&a11;
            #pragma unroll
            for (int j = 0; j < 4; j++) { o[j] = f2b(f2[j]); o[4+j] = f2b(f3[j]); }
            *(uint4*)wA1 = *(const uint4*)o;
        }
        __syncthreads();
        // prefetch next K-step's A registers; streams under the MFMA phase
        if (kt + 64 < kb + 512) {
            a00 = *(const float4*)(pA0 + kt + 64);
            a01 = *(const float4*)(pA0 + kt + 64 + 4);
            a10 = *(const float4*)(pA1 + kt + 64);
            a11 = *(const float4*)(pA1 + kt + 64 + 4);
        }
        #pragma unroll
        for (int ks = 0; ks < 2; ks++) {
            bf16x8 a[4], b[6];
            #pragma unroll
            for (int mb = 0; mb < 4; mb++) {
                int r = wm*64 + mb*16 + lr;
                int c = (ks*4 + quad) ^ (r & 7);
                a[mb] = *(const bf16x8*)&lA[(r*8 + c)*8];
            }
            #pragma unroll
            for (int nb = 0; nb < 6; nb++) {
                int r = wn*96 + nb*16 + lr;
                int c = (ks*4 + quad) ^ (r & 7);
                b[nb] = *(const bf16x8*)&lB[(r*8 + c)*8];
            }
            #pragma unroll
            for (int mb = 0; mb < 4; mb++)
                #pragma unroll
                for (int nb = 0; nb < 6; nb++)
                    acc[mb][nb] = MFMA(a[mb], b[nb], acc[mb][nb]);
        }
        __syncthreads();
    }

    // write partials: slab (z*3 + ct), same layout as before -> epi unchanged
    unsigned short* base = AccB + (size_t)blockIdx.y * 3 * Nrow * 128;
    #pragma unroll
    for (int mb = 0; mb < 4; mb++)
        #pragma unroll
        for (int nb = 0; nb < 6; nb++)
            #pragma unroll
            for (int rg = 0; rg < 4; rg++) {
                int s_ = wm*64 + mb*16 + quad*4 + rg;
                int n  = wn*96 + nb*16 + lr;           // 0..383
                int ct = n >> 7, e_ = n & 127;
                base[(size_t)ct*Nrow*128 + (size_t)(row0 + s_)*128 + e_] =
                    f2b(acc[mb][nb][rg]);
            }
}

// epilogue: sum 4 bf16 partial slabs -> sigma (q,k) -> bf16 Q/K/V
__global__ void k_qkv_epi(const unsigned short* __restrict__ AccB,
                          unsigned short* __restrict__ Qb,
                          unsigned short* __restrict__ Kb, unsigned short* __restrict__ Vb)
{
    int gid = blockIdx.x*256 + threadIdx.x;      // 393216 threads, 8 elems each
    int ct = gid / (Nrow*16);
    int off = (gid - ct*Nrow*16) * 8;
    float vs[8];
    #pragma unroll
    for (int j = 0; j < 8; j++) vs[j] = 0.f;
    #pragma unroll
    for (int s = 0; s < 4; s++) {
        uint4 u = *(const uint4*)&AccB[((size_t)s*3 + ct)*Nrow*128 + off];
        const unsigned short* us = (const unsigned short*)&u;
        #pragma unroll
        for (int j = 0; j < 8; j++) vs[j] += b2f(us[j]);
    }
    unsigned short o[8];
    if (ct < 2) {
        #pragma unroll
        for (int j = 0; j < 8; j++) o[j] = f2b(sig_elu(vs[j]));
    } else {
        #pragma unroll
        for (int j = 0; j < 8; j++) o[j] = f2b(vs[j]);
    }
    unsigned short* dst = (ct == 0) ? Qb : (ct == 1 ? Kb : Vb);
    *(uint4*)&dst[off] = *(const uint4*)o;
}

// per (chunk, e-quarter): vret=(K̃M)/(K̃·z+eps); Mpart[:,eq]=K̃^T(V-vret)[:,eq];
// KV[:,eq]=K̃^T V[:,eq]; ksum (eq==0 only). K̃^T staged once, reused as A twice.
__global__ __launch_bounds__(256, 2) void k_delta_kv(
    const unsigned short* __restrict__ Kb, const unsigned short* __restrict__ Vb,
    const unsigned short* __restrict__ MbT, const float* __restrict__ z,
    float* __restrict__ KV, float* __restrict__ ksum, float* __restrict__ Mpart)
{
    __shared__ unsigned short b0[128*128];   // K̃ then K̃^T
    __shared__ unsigned short b1a[32*128];   // M^T quarter, B
    __shared__ unsigned short b1b[32*128];   // W = V - vret, B
    __shared__ unsigned short b1c[32*128];   // V quarter, B
    __shared__ float den[128];
    const int tid = threadIdx.x;
    const int c = blockIdx.x, t0 = c*128;
    const int e0 = blockIdx.y * 32;
    const int wave = tid >> 6, lane = tid & 63;
    const int wm = wave >> 1, wn = wave & 1, quad = lane >> 4, lr = lane & 15;

    stage_dir<128>(b0, Kb + (size_t)t0*Dsz, Dsz, tid);   // K̃ (A)
    stage_dir<32>(b1a, MbT + (size_t)e0*128, 128, tid);  // M^T quarter (B)
    __syncthreads();                                     // #1

    f32x4 acc1[4][1]; zaccg(acc1);
    mmg<4,1>(b0, b1a, acc1, wm, wn, quad, lr);           // vret_num[t][el]

    if (tid < 128) {                                     // den[t] = K̃[t]·z + eps
        float p = 0.f;
        for (int d = 0; d < 128; d++)
            p += b2f(b0[swzR(tid, d >> 3, 128) + (d & 7)]) * z[d];
        den[tid] = p + EPSF;
    }
    __syncthreads();                                     // #2

    stage_T128(b0, Kb + (size_t)t0*Dsz, Dsz, tid);       // K̃^T (A: elem (d,t))
    stage_T32(b1c, Vb + (size_t)t0*Dsz, Dsz, e0, tid);   // V quarter (B: elem (el,t))
    #pragma unroll
    for (int mb = 0; mb < 4; mb++)                       // b1b <- W = V - vret
        #pragma unroll
        for (int rg = 0; rg < 4; rg++) {
            int s_ = wm*64 + mb*16 + quad*4 + rg;
            int el = wn*16 + lr;
            float v = b2f(Vb[(size_t)(t0 + s_)*Dsz + e0 + el]);
            float w = v - acc1[mb][0][rg] / den[s_];
            b1b[swzR(el, s_ >> 3, 32) + (s_ & 7)] = f2b(w);
        }
    __syncthreads();                                     // #3

    if (e0 == 0 && tid < 128) {                          // ksum[d] = sum_t K̃[t][d]
        float p = 0.f;
        for (int t = 0; t < 128; t++)
            p += b2f(b0[swzR(tid, t >> 3, 128) + (t & 7)]);
        ksum[(size_t)c*128 + tid] = p;
    }
    f32x4 acc2[4][1]; zaccg(acc2);
    mmg<4,1>(b0, b1b, acc2, wm, wn, quad, lr);           // Mpart[d][el]
    f32x4 acc3[4][1]; zaccg(acc3);
    mmg<4,1>(b0, b1c, acc3, wm, wn, quad, lr);           // KV[d][el]
    #pragma unroll
    for (int mb = 0; mb < 4; mb++)
        #pragma unroll
        for (int rg = 0; rg < 4; rg++) {
            int d_ = wm*64 + mb*16 + quad*4 + rg;
            int el = wn*16 + lr;
            Mpart[(size_t)c*16384 + (size_t)d_*128 + e0 + el] = acc2[mb][0][rg];
            KV[(size_t)c*16384 + (size_t)d_*128 + e0 + el]    = acc3[mb][0][rg];
        }
}

// fused: exclusive chunk-prefix of KV (-> bf16) and ksum, plus final M_new / z_new
__global__ void k_scan_final(
    const float* __restrict__ KV, const float* __restrict__ ksum,
    const float* __restrict__ M, const float* __restrict__ z,
    const float* __restrict__ Mpart, unsigned short* __restrict__ KVp,
    float* __restrict__ kpre, float* __restrict__ omz)
{
    int idx = blockIdx.x*256 + threadIdx.x;
    if (idx < 32768) {                       // KV scan (per batch)
        int batch = idx >> 14, ed = idx & 16383;
        float a = 0.f;
        #pragma unroll 8
        for (int i = 0; i < CPB; i++) {
            size_t cc = (size_t)(batch*CPB + i);
            KVp[cc*16384 + ed] = f2b(a);
            a += KV[cc*16384 + ed];
        }
    } else if (idx < 33024) {                // ksum scan
        int j = idx - 32768; int batch = j >> 7, d = j & 127;
        float a = 0.f;
        #pragma unroll 8
        for (int i = 0; i < CPB; i++) {
            int cc = batch*CPB + i;
            kpre[cc*128 + d] = a;
            a += ksum[cc*128 + d];
        }
    } else if (idx < 49408) {                // M_new
        int m = idx - 33024;
        float a = M[m];
        #pragma unroll 8
        for (int cc = 0; cc < NCH; cc++) a += Mpart[(size_t)cc*16384 + m];
        omz[m] = a;
    } else if (idx < 49536) {                // z_new
        int d = idx - 49408;
        float a = z[d];
        #pragma unroll 8
        for (int cc = 0; cc < NCH; cc++) a += ksum[cc*128 + d];
        omz[16384 + d] = a;
    }
}

// fused attention per (chunk, e-quarter): memory-retrieve + inter + intra causal -> P bf16
__global__ __launch_bounds__(256, 2) void k_attn(
    const unsigned short* __restrict__ Qb, const unsigned short* __restrict__ KVp,
    const float* __restrict__ kpre, const unsigned short* __restrict__ MbT,
    const float* __restrict__ z, const float* __restrict__ gate,
    const unsigned short* __restrict__ Kb, const unsigned short* __restrict__ Vb,
    unsigned short* __restrict__ P)
{
    __shared__ unsigned short b0[128*128];   // Q̃, then masked S
    __shared__ unsigned short b1[128*128];   // [Mq|KVpq] then K̃ then Vq
    __shared__ float dmem[128], dl[128], rs[128];
    const int tid = threadIdx.x;
    const int c = blockIdx.x, t0 = c*128;
    const int e0 = blockIdx.y * 32;
    const int wave = tid >> 6, lane = tid & 63;
    const int wm = wave >> 1, wn = wave & 1, quad = lane >> 4, lr = lane & 15;
    unsigned short* b1q0 = b1;
    unsigned short* b1q1 = b1 + 32*128;

    if (tid < 128) rs[tid] = 0.f;
    stage_dir<128>(b0, Qb + (size_t)t0*Dsz, Dsz, tid);          // Q̃ (A)
    stage_dir<32>(b1q0, MbT + (size_t)e0*128, 128, tid);        // M^T quarter (B)
    stage_T32(b1q1, KVp + (size_t)c*16384, 128, e0, tid);       // KVpre quarter (B: (el,d))
    __syncthreads();                                            // #1

    if (tid < 128) {                                            // dmem = Q̃·z + eps
        float p = 0.f;
        for (int d = 0; d < 128; d++)
            p += b2f(b0[swzR(tid, d >> 3, 128) + (d & 7)]) * z[d];
        dmem[tid] = p + EPSF;
    } else {                                                    // dl = Q̃·kpre
        int s_ = tid - 128; float p = 0.f;
        for (int d = 0; d < 128; d++)
            p += b2f(b0[swzR(s_, d >> 3, 128) + (d & 7)]) * kpre[c*128 + d];
        dl[s_] = p;
    }
    f32x4 accM[4][1]; zaccg(accM);
    mmg<4,1>(b0, b1q0, accM, wm, wn, quad, lr);                 // mem_num[t][el]
    f32x4 accN[4][1]; zaccg(accN);
    mmg<4,1>(b0, b1q1, accN, wm, wn, quad, lr);                 // inter numerator
    __syncthreads();                                            // #2

    float g = 1.f / (1.f + expf(-gate[0]));
    f32x4 base[4][1];
    #pragma unroll
    for (int mb = 0; mb < 4; mb++)
        #pragma unroll
        for (int rg = 0; rg < 4; rg++) {
            int s_ = wm*64 + mb*16 + quad*4 + rg;
            base[mb][0][rg] = g * accM[mb][0][rg] / dmem[s_];
        }
    stage_dir<128>(b1, Kb + (size_t)t0*Dsz, Dsz, tid);          // K̃ full (B for S)
    __syncthreads();                                            // #3

    f32x4 accS[4][4]; zaccg(accS);
    mmg<4,4>(b0, b1, accS, wm, wn, quad, lr);                   // S[s][t]
    __syncthreads();                                            // #4

    #pragma unroll
    for (int mb = 0; mb < 4; mb++)                              // mask + rowsum + S -> b0 (A)
        #pragma unroll
        for (int rg = 0; rg < 4; rg++) {
            int s_ = wm*64 + mb*16 + quad*4 + rg;
            float part = 0.f;
            #pragma unroll
            for (int nb = 0; nb < 4; nb++) {
                int t_ = wn*64 + nb*16 + lr;
                float v = (t_ <= s_) ? accS[mb][nb][rg] : 0.f;
                part += v;
                b0[swzR(s_, t_ >> 3, 128) + (t_ & 7)] = f2b(v);
            }
            #pragma unroll
            for (int m = 1; m < 16; m <<= 1) part += __shfl_xor(part, m, 64);
            if (lr == 0) atomicAdd(&rs[s_], part);
        }
    stage_T32(b1q0, Vb + (size_t)t0*Dsz, Dsz, e0, tid);         // V quarter (B: (el,t))
    __syncthreads();                                            // #5

    f32x4 accV[4][1]; zaccg(accV);
    mmg<4,1>(b0, b1q0, accV, wm, wn, quad, lr);                 // intra numerator

    #pragma unroll
    for (int mb = 0; mb < 4; mb++)
        #pragma unroll
        for (int rg = 0; rg < 4; rg++) {
            int s_ = wm*64 + mb*16 + quad*4 + rg;
            int el = wn*16 + lr;
            float num = accN[mb][0][rg] + accV[mb][0][rg];
            float dd  = dl[s_] + rs[s_] + EPSF;
            float val = base[mb][0][rg] + (1.f - g) * num / dd;
            P[(size_t)(t0 + s_)*Dsz + e0 + el] = f2b(val);
        }
}

// out = P[8192,128] @ Wo[2048,128]^T, fp32; global_load_lds staging (XOR-permuted)
__global__ __launch_bounds__(256, 2) void k_gemm_out(
    const unsigned short* __restrict__ P, const unsigned short* __restrict__ Wo,
    float* __restrict__ out)
{
    __shared__ unsigned short b0[128*128];   // chunk p = r*16 + (kc^(r&15))
    __shared__ unsigned short b1[128*128];
    const int tid = threadIdx.x;
    const int row0 = blockIdx.x*128, n0 = blockIdx.y*128;
    const int wave = tid >> 6, lane = tid & 63;
    const int wm = wave >> 1, wn = wave & 1, quad = lane >> 4, lr = lane & 15;

    #pragma unroll
    for (int i = 0; i < 8; i++) {
        int p = tid + i*256; int r = p >> 4; int kc = (p & 15) ^ (r & 15);
        gll16(P + (size_t)(row0 + r)*Dsz + kc*8, &b0[p*8]);
    }
    #pragma unroll
    for (int i = 0; i < 8; i++) {
        int p = tid + i*256; int r = p >> 4; int kc = (p & 15) ^ (r & 15);
        gll16(Wo + (size_t)(n0 + r)*Dsz + kc*8, &b1[p*8]);
    }
    __syncthreads();

    f32x4 acc[4][4]; zaccg(acc);
    #pragma unroll
    for (int ks = 0; ks < 4; ks++) {
        bf16x8 a[4], b[4];
        #pragma unroll
        for (int mb = 0; mb < 4; mb++) {
            int r = wm*64 + mb*16 + lr;
            a[mb] = *(const bf16x8*)&b0[(r*16 + ((ks*4 + quad) ^ (r & 15)))*8];
        }
        #pragma unroll
        for (int nb = 0; nb < 4; nb++) {
            int r = wn*64 + nb*16 + lr;
            b[nb] = *(const bf16x8*)&b1[(r*16 + ((ks*4 + quad) ^ (r & 15)))*8];
        }
        #pragma unroll
        for (int mb = 0; mb < 4; mb++)
            #pragma unroll
            for (int nb = 0; nb < 4; nb++)
                acc[mb][nb] = MFMA(a[mb], b[nb], acc[mb][nb]);
    }
    #pragma unroll
    for (int mb = 0; mb < 4; mb++)
        #pragma unroll
        for (int nb = 0; nb < 4; nb++)
            #pragma unroll
            for (int rg = 0; rg < 4; rg++) {
                int s_ = wm*64 + mb*16 + quad*4 + rg;
                int e_ = wn*64 + nb*16 + lr;
                out[(size_t)(row0 + s_)*Hsz + n0 + e_] = acc[mb][nb][rg];
            }
}

// ---------------- launcher ----------------
extern "C" void kernel_launch(void* const* d_in, const int* in_sizes, int n_in,
                              void* d_out, int out_size, void* d_ws, size_t ws_size,
                              hipStream_t stream)
{
    const float* X    = (const float*)d_in[0];
    const float* wq   = (const float*)d_in[1];
    const float* wk   = (const float*)d_in[2];
    const float* wv   = (const float*)d_in[3];
    const float* wo   = (const float*)d_in[4];
    const float* gate = (const float*)d_in[5];
    const float* M    = (const float*)d_in[6];
    const float* z    = (const float*)d_in[7];

    char* ws = (char*)d_ws;
    unsigned short* Wfull = (unsigned short*)(ws + WQKV_OFF);
    unsigned short* Wo_b  = (unsigned short*)(ws + WO_OFF);
    unsigned short* MbT   = (unsigned short*)(ws + MBT_OFF);
    unsigned short* Qb    = (unsigned short*)(ws + QB_OFF);
    unsigned short* Kb    = (unsigned short*)(ws + KB_OFF);
    unsigned short* Vb    = (unsigned short*)(ws + VB_OFF);
    unsigned short* Pb    = (unsigned short*)(ws + PB_OFF);
    unsigned short* AccB  = (unsigned short*)(ws + ACC_OFF);
    float* KV    = (float*)(ws + KV_OFF);
    unsigned short* KVp = (unsigned short*)(ws + KVP_OFF);
    float* Mpart = (float*)(ws + MPART_OFF);
    float* ksum  = (float*)(ws + KSUM_OFF);
    float* kpre  = (float*)(ws + KPRE_OFF);

    float* outp   = (float*)d_out;
    float* out_mz = outp + (size_t)Nrow*Hsz;

    k_cvt_w<<<((4*WN + 16384)/4 + 255)/256, 256, 0, stream>>>(wq, wk, wv, wo, M, Wfull, MbT);
    k_gemm_qkv<<<dim3(Nrow/128, 4), 512, 0, stream>>>(X, Wfull, AccB);
    k_qkv_epi<<<(3*Nrow*16)/256, 256, 0, stream>>>(AccB, Qb, Kb, Vb);
    k_delta_kv<<<dim3(NCH, 4), 256, 0, stream>>>(Kb, Vb, MbT, z, KV, ksum, Mpart);
    k_scan_final<<<194, 256, 0, stream>>>(KV, ksum, M, z, Mpart, KVp, kpre, out_mz);
    k_attn<<<dim3(NCH, 4), 256, 0, stream>>>(Qb, KVp, kpre, MbT, z, gate, Kb, Vb, Pb);
    k_gemm_out<<<dim3(Nrow/128, Hsz/128), 256, 0, stream>>>(Pb, Wo_b, outp);
}

// Round 2
// 178.606 us; speedup vs baseline: 1.0090x; 1.0090x over previous
//
#include <hip/hip_runtime.h>
#include <hip/hip_bf16.h>
#include <math.h>

#define DI __device__ __forceinline__

typedef __bf16 bf16x8 __attribute__((ext_vector_type(8)));
typedef float  f32x4  __attribute__((ext_vector_type(4)));

static constexpr int   Bsz  = 2, Ssz = 4096, Hsz = 2048, Dsz = 128;
static constexpr int   Nrow = Bsz * Ssz;     // 8192
static constexpr int   NCH  = Nrow / 128;    // 64 chunks
static constexpr int   CPB  = Ssz / 128;     // 32 chunks per batch
static constexpr int   WN   = Dsz * Hsz;     // 262144
static constexpr float EPSF = 1e-6f;

// ---------------- workspace layout (bytes) ----------------
static constexpr size_t WQKV_OFF = 0;                            // bf16 [384][2048]
static constexpr size_t WO_OFF   = (size_t)3*WN*2;               // bf16 [2048][128]
static constexpr size_t MB_OFF   = WO_OFF + (size_t)WN*2;        // bf16 [128][128] (cvt spill)
static constexpr size_t MBT_OFF  = MB_OFF + 32768;               // bf16 M^T [128][128]
static constexpr size_t QB_OFF   = MBT_OFF + 32768;              // bf16 [8192][128]
static constexpr size_t KB_OFF   = QB_OFF + (size_t)Nrow*Dsz*2;
static constexpr size_t VB_OFF   = KB_OFF + (size_t)Nrow*Dsz*2;
static constexpr size_t PB_OFF   = VB_OFF + (size_t)Nrow*Dsz*2;
static constexpr size_t ACC_OFF  = PB_OFF + (size_t)Nrow*Dsz*2;  // bf16 [4][3][8192][128] = 25.2MB
// --- aliased into ACC region (dead after k_qkv_epi) ---
static constexpr size_t KV_OFF   = ACC_OFF;                      // f32 [64][128d][128e] 4MB
static constexpr size_t KVP_OFF  = ACC_OFF + (size_t)4*1024*1024;// bf16 [64][128d][128e] 2MB
static constexpr size_t MPART_OFF= ACC_OFF + (size_t)6*1024*1024;// f32 [64][128][128] 4MB
static constexpr size_t KSUM_OFF = ACC_OFF + (size_t)10*1024*1024;// f32 [64][128]
static constexpr size_t KPRE_OFF = KSUM_OFF + 32768;             // f32 [64][128]

// ---------------- helpers ----------------
DI float b2f(unsigned short u) {
    union { float f; unsigned int i; } x; x.i = ((unsigned int)u) << 16; return x.f;
}
DI unsigned short f2b(float f) {
    __bf16 h = (__bf16)f; return __builtin_bit_cast(unsigned short, h);
}
DI float sig_elu(float x) { return x > 0.f ? x + 1.f : expf(x); }

DI f32x4 MFMA(bf16x8 a, bf16x8 b, f32x4 c) {
    return __builtin_amdgcn_mfma_f32_16x16x32_bf16(a, b, c, 0, 0, 0);
}
template<int NB>
DI void zaccg(f32x4 (&acc)[4][NB]) {
    f32x4 zz = {0.f, 0.f, 0.f, 0.f};
    #pragma unroll
    for (int i = 0; i < 4; i++)
        #pragma unroll
        for (int j = 0; j < NB; j++) acc[i][j] = zz;
}
template<int NB>
DI void zacc2(f32x4 (&acc)[2][NB]) {
    f32x4 zz = {0.f, 0.f, 0.f, 0.f};
    #pragma unroll
    for (int i = 0; i < 2; i++)
        #pragma unroll
        for (int j = 0; j < NB; j++) acc[i][j] = zz;
}

// async 16B global -> LDS (DMA, bypasses VGPRs). LDS dst = wave-uniform base + lane*16.
DI void gll16(const void* g, void* l) {
    __builtin_amdgcn_global_load_lds((const __attribute__((address_space(1))) void*)g,
                                     (__attribute__((address_space(3))) void*)l, 16, 0, 0);
}

// swizzled chunk offset (ushorts) of 8-elem chunk (r, kc) in a VALU-staged operand
// tile with R rows (XOR banking)
DI int swzR(int r, int kc, int R) { return (kc*R + (r ^ (kc & 7))) * 8; }

// generic matmul out of swzR-layout LDS: A 128 rows, B NB*32 rows
template<int NKS, int NB>
DI void mmg(const unsigned short* A, const unsigned short* Bm, f32x4 (&acc)[4][NB],
            int wm, int wn, int quad, int lr) {
    #pragma unroll
    for (int ks = 0; ks < NKS; ks++) {
        bf16x8 a[4], b[NB];
        #pragma unroll
        for (int mb = 0; mb < 4; mb++)
            a[mb] = *(const bf16x8*)&A[swzR(wm*64 + mb*16 + lr, ks*4 + quad, 128)];
        #pragma unroll
        for (int nb = 0; nb < NB; nb++)
            b[nb] = *(const bf16x8*)&Bm[swzR(wn*(NB*16) + nb*16 + lr, ks*4 + quad, NB*32)];
        #pragma unroll
        for (int mb = 0; mb < 4; mb++)
            #pragma unroll
            for (int nb = 0; nb < NB; nb++)
                acc[mb][nb] = MFMA(a[mb], b[nb], acc[mb][nb]);
    }
}

// matmul with 64-row A tile: rows = wm*32 + mb*16, mb<2
template<int NKS, int NB>
DI void mmg64(const unsigned short* A, const unsigned short* Bm, f32x4 (&acc)[2][NB],
              int wm, int wn, int quad, int lr) {
    #pragma unroll
    for (int ks = 0; ks < NKS; ks++) {
        bf16x8 a[2], b[NB];
        #pragma unroll
        for (int mb = 0; mb < 2; mb++)
            a[mb] = *(const bf16x8*)&A[swzR(wm*32 + mb*16 + lr, ks*4 + quad, 64)];
        #pragma unroll
        for (int nb = 0; nb < NB; nb++)
            b[nb] = *(const bf16x8*)&Bm[swzR(wn*(NB*16) + nb*16 + lr, ks*4 + quad, NB*32)];
        #pragma unroll
        for (int mb = 0; mb < 2; mb++)
            #pragma unroll
            for (int nb = 0; nb < NB; nb++)
                acc[mb][nb] = MFMA(a[mb], b[nb], acc[mb][nb]);
    }
}

// row-major [R][128] bf16 tile -> swzR operand layout (VALU path)
template<int R>
DI void stage_dir(unsigned short* dst, const unsigned short* src, int src_ld, int tid) {
    #pragma unroll
    for (int i = 0; i < R/16; i++) {
        int s = tid + i*256; int r = s >> 4, kc = s & 15;
        *(uint4*)&dst[swzR(r, kc, R)] = *(const uint4*)(src + (size_t)r*src_ld + kc*8);
    }
}

// transposed staging (full 128): operand elem (r=col, k=row) <- src[row][col]
DI void stage_T128(unsigned short* dst, const unsigned short* src, int src_ld, int tid) {
    #pragma unroll
    for (int i = 0; i < 8; i++) {
        int s = tid + i*256;
        int rw = (s & 15) + ((s >> 8) << 4);
        int c0 = ((s >> 4) & 15) * 8;
        unsigned short tmp[8];
        *(uint4*)tmp = *(const uint4*)(src + (size_t)rw*src_ld + c0);
        #pragma unroll
        for (int j = 0; j < 8; j++)
            dst[swzR(c0 + j, rw >> 3, 128) + (rw & 7)] = tmp[j];
    }
}

// transposed staging into 64-row operand: elem (r=col-colOff, k=row) <- src[row][colOff+col]
DI void stage_T64(unsigned short* dst, const unsigned short* src, int src_ld, int colOff, int tid) {
    #pragma unroll
    for (int i = 0; i < 4; i++) {
        int s = tid + i*256;                 // 0..1023
        int rw = s >> 3;                     // row 0..127
        int c0 = (s & 7) * 8;                // col 0..56
        unsigned short tmp[8];
        *(uint4*)tmp = *(const uint4*)(src + (size_t)rw*src_ld + colOff + c0);
        #pragma unroll
        for (int j = 0; j < 8; j++)
            dst[swzR(c0 + j, rw >> 3, 64) + (rw & 7)] = tmp[j];
    }
}

// transposed staging into 32-row operand: elem (r=col-colOff, k=row) <- src[row][colOff+col]
DI void stage_T32(unsigned short* dst, const unsigned short* src, int src_ld, int colOff, int tid) {
    #pragma unroll
    for (int i = 0; i < 2; i++) {
        int s = tid + i*256;                     // 0..511
        int rw = (s & 15) + ((s >> 6) << 4);     // 0..127
        int c0 = ((s >> 4) & 3) * 8;             // 0..24
        unsigned short tmp[8];
        *(uint4*)tmp = *(const uint4*)(src + (size_t)rw*src_ld + colOff + c0);
        #pragma unroll
        for (int j = 0; j < 8; j++)
            dst[swzR(c0 + j, rw >> 3, 32) + (rw & 7)] = tmp[j];
    }
}

// ---------------- kernels ----------------

// fused weight conversion: wq|wk|wv -> Wqkv, wo -> Wo, M -> (spill) and MbT
__global__ void k_cvt_w(const float* __restrict__ wq, const float* __restrict__ wk,
                        const float* __restrict__ wv, const float* __restrict__ wo,
                        const float* __restrict__ M, unsigned short* __restrict__ dst,
                        unsigned short* __restrict__ MbT)
{
    int gid = blockIdx.x*256 + threadIdx.x;
    if (gid >= (4*WN + 16384)/4) return;
    int e = gid*4;
    const float* src; int rel;
    if      (e < WN)     { src = wq; rel = e; }
    else if (e < 2*WN)   { src = wk; rel = e - WN; }
    else if (e < 3*WN)   { src = wv; rel = e - 2*WN; }
    else if (e < 4*WN)   { src = wo; rel = e - 3*WN; }
    else                 { src = M;  rel = e - 4*WN; }
    float4 v = *(const float4*)(src + rel);
    const float* vf = (const float*)&v;
    unsigned short o[4];
    #pragma unroll
    for (int j = 0; j < 4; j++) o[j] = f2b(vf[j]);
    *(uint2*)&dst[e] = *(const uint2*)o;
    if (e >= 4*WN) {
        #pragma unroll
        for (int j = 0; j < 4; j++) {
            int d = (rel + j) >> 7, ee = (rel + j) & 127;
            MbT[ee*128 + d] = o[j];
        }
    }
}

// QKV projection, single X pass: X[8192,2048]fp32 @ Wqkv[384,2048]^T
__global__ __launch_bounds__(512, 2) void k_gemm_qkv(
    const float* __restrict__ X, const unsigned short* __restrict__ W,
    unsigned short* __restrict__ AccB)
{
    __shared__ unsigned short lA[128*64];   // bf16, chunk slot p = r*8 + (kc^(r&7))   16KB
    __shared__ unsigned short lB[384*64];   // bf16, chunk slot p = r*8 + (kc^(r&7))   48KB
    const int tid = threadIdx.x;            // 0..511
    const int row0 = blockIdx.x * 128;
    const int kb   = blockIdx.y * 512;      // K-split of 4
    const int wave = tid >> 6, lane = tid & 63;
    const int wm = wave >> 2, wn = wave & 3;      // wm 0..1 (64 rows), wn 0..3 (96 cols)
    const int quad = lane >> 4, lr = lane & 15;

    const int cA0 = tid, cA1 = tid + 512;
    const int rA0 = cA0 >> 3, kA0 = cA0 & 7;
    const int rA1 = cA1 >> 3, kA1 = cA1 & 7;
    const float* pA0 = X + (size_t)(row0 + rA0)*Hsz + kA0*8;
    const float* pA1 = X + (size_t)(row0 + rA1)*Hsz + kA1*8;
    unsigned short* wA0 = &lA[(rA0*8 + (kA0 ^ (rA0 & 7)))*8];
    unsigned short* wA1 = &lA[(rA1*8 + (kA1 ^ (rA1 & 7)))*8];

    f32x4 acc[4][6];
    {
        f32x4 zz = {0.f, 0.f, 0.f, 0.f};
        #pragma unroll
        for (int i = 0; i < 4; i++)
            #pragma unroll
            for (int j = 0; j < 6; j++) acc[i][j] = zz;
    }

    float4 a00 = *(const float4*)(pA0 + kb);
    float4 a01 = *(const float4*)(pA0 + kb + 4);
    float4 a10 = *(const float4*)(pA1 + kb);
    float4 a11 = *(const float4*)(pA1 + kb + 4);

    for (int kt = kb; kt < kb + 512; kt += 64) {
        #pragma unroll
        for (int i = 0; i < 6; i++) {
            int p = tid + i*512; int r = p >> 3; int kc = (p & 7) ^ (r & 7);
            gll16(W + (size_t)r*Hsz + kt + kc*8, &lB[p*8]);
        }
        {
            unsigned short o[8];
            const float* f0 = (const float*)&a00; const float* f1 = (const float*)&a01;
            #pragma unroll
            for (int j = 0; j < 4; j++) { o[j] = f2b(f0[j]); o[4+j] = f2b(f1[j]); }
            *(uint4*)wA0 = *(const uint4*)o;
            const float* f2 = (const float*)&a10; const float* f3 = (const float*)&a11;
            #pragma unroll
            for (int j = 0; j < 4; j++) { o[j] = f2b(f2[j]); o[4+j] = f2b(f3[j]); }
            *(uint4*)wA1 = *(const uint4*)o;
        }
        __syncthreads();
        if (kt + 64 < kb + 512) {
            a00 = *(const float4*)(pA0 + kt + 64);
            a01 = *(const float4*)(pA0 + kt + 64 + 4);
            a10 = *(const float4*)(pA1 + kt + 64);
            a11 = *(const float4*)(pA1 + kt + 64 + 4);
        }
        #pragma unroll
        for (int ks = 0; ks < 2; ks++) {
            bf16x8 a[4], b[6];
            #pragma unroll
            for (int mb = 0; mb < 4; mb++) {
                int r = wm*64 + mb*16 + lr;
                int c = (ks*4 + quad) ^ (r & 7);
                a[mb] = *(const bf16x8*)&lA[(r*8 + c)*8];
            }
            #pragma unroll
            for (int nb = 0; nb < 6; nb++) {
                int r = wn*96 + nb*16 + lr;
                int c = (ks*4 + quad) ^ (r & 7);
                b[nb] = *(const bf16x8*)&lB[(r*8 + c)*8];
            }
            #pragma unroll
            for (int mb = 0; mb < 4; mb++)
                #pragma unroll
                for (int nb = 0; nb < 6; nb++)
                    acc[mb][nb] = MFMA(a[mb], b[nb], acc[mb][nb]);
        }
        __syncthreads();
    }

    unsigned short* base = AccB + (size_t)blockIdx.y * 3 * Nrow * 128;
    #pragma unroll
    for (int mb = 0; mb < 4; mb++)
        #pragma unroll
        for (int nb = 0; nb < 6; nb++)
            #pragma unroll
            for (int rg = 0; rg < 4; rg++) {
                int s_ = wm*64 + mb*16 + quad*4 + rg;
                int n  = wn*96 + nb*16 + lr;           // 0..383
                int ct = n >> 7, e_ = n & 127;
                base[(size_t)ct*Nrow*128 + (size_t)(row0 + s_)*128 + e_] =
                    f2b(acc[mb][nb][rg]);
            }
}

// epilogue: sum 4 bf16 partial slabs -> sigma (q,k) -> bf16 Q/K/V
__global__ void k_qkv_epi(const unsigned short* __restrict__ AccB,
                          unsigned short* __restrict__ Qb,
                          unsigned short* __restrict__ Kb, unsigned short* __restrict__ Vb)
{
    int gid = blockIdx.x*256 + threadIdx.x;      // 393216 threads, 8 elems each
    int ct = gid / (Nrow*16);
    int off = (gid - ct*Nrow*16) * 8;
    float vs[8];
    #pragma unroll
    for (int j = 0; j < 8; j++) vs[j] = 0.f;
    #pragma unroll
    for (int s = 0; s < 4; s++) {
        uint4 u = *(const uint4*)&AccB[((size_t)s*3 + ct)*Nrow*128 + off];
        const unsigned short* us = (const unsigned short*)&u;
        #pragma unroll
        for (int j = 0; j < 8; j++) vs[j] += b2f(us[j]);
    }
    unsigned short o[8];
    if (ct < 2) {
        #pragma unroll
        for (int j = 0; j < 8; j++) o[j] = f2b(sig_elu(vs[j]));
    } else {
        #pragma unroll
        for (int j = 0; j < 8; j++) o[j] = f2b(vs[j]);
    }
    unsigned short* dst = (ct == 0) ? Qb : (ct == 1 ? Kb : Vb);
    *(uint4*)&dst[off] = *(const uint4*)o;
}

// per (chunk, e-quarter, d-half): vret=(K̃M)/(K̃·z+eps); Mpart[dh,:][eq]=K̃^T(V-vret);
// KV[dh,:][eq]=K̃^T V; ksum (eq==0,dh==0 only). 512 blocks -> 2 blocks/CU.
__global__ __launch_bounds__(256, 2) void k_delta_kv(
    const unsigned short* __restrict__ Kb, const unsigned short* __restrict__ Vb,
    const unsigned short* __restrict__ MbT, const float* __restrict__ z,
    float* __restrict__ KV, float* __restrict__ ksum, float* __restrict__ Mpart)
{
    __shared__ unsigned short b0[128*128];   // K̃ (dir, full)        32KB
    __shared__ unsigned short bA[64*128];    // K̃^T d-half (A)       16KB
    __shared__ unsigned short b1a[32*128];   // M^T quarter, B        8KB
    __shared__ unsigned short b1b[32*128];   // W = V - vret, B       8KB
    __shared__ unsigned short b1c[32*128];   // V quarter, B          8KB
    __shared__ float den[128];
    const int tid = threadIdx.x;
    const int c = blockIdx.x, t0 = c*128;
    const int e0 = blockIdx.y * 32;
    const int dh = blockIdx.z;               // d-half 0/1
    const int wave = tid >> 6, lane = tid & 63;
    const int wm = wave >> 1, wn = wave & 1, quad = lane >> 4, lr = lane & 15;

    stage_dir<128>(b0, Kb + (size_t)t0*Dsz, Dsz, tid);     // K̃ (A for vret)
    stage_T64(bA, Kb + (size_t)t0*Dsz, Dsz, dh*64, tid);   // K̃^T d-half
    stage_dir<32>(b1a, MbT + (size_t)e0*128, 128, tid);    // M^T quarter (B)
    stage_T32(b1c, Vb + (size_t)t0*Dsz, Dsz, e0, tid);     // V quarter (B: (el,t))
    __syncthreads();                                       // #1

    f32x4 acc1[4][1]; zaccg(acc1);
    mmg<4,1>(b0, b1a, acc1, wm, wn, quad, lr);             // vret_num[t][el] (full t)

    if (tid < 128) {                                       // den[t] = K̃[t]·z + eps
        float p = 0.f;
        for (int d = 0; d < 128; d++)
            p += b2f(b0[swzR(tid, d >> 3, 128) + (d & 7)]) * z[d];
        den[tid] = p + EPSF;
        if (e0 == 0 && dh == 0) {                          // ksum[d] = sum_t K̃[t][d]
            float q = 0.f;
            for (int t = 0; t < 128; t++)
                q += b2f(b0[swzR(t, tid >> 3, 128) + (tid & 7)]);
            ksum[(size_t)c*128 + tid] = q;
        }
    }
    __syncthreads();                                       // #2 (den ready)

    #pragma unroll
    for (int mb = 0; mb < 4; mb++)                         // b1b <- W = V - vret
        #pragma unroll
        for (int rg = 0; rg < 4; rg++) {
            int s_ = wm*64 + mb*16 + quad*4 + rg;
            int el = wn*16 + lr;
            float v = b2f(Vb[(size_t)(t0 + s_)*Dsz + e0 + el]);
            float w = v - acc1[mb][0][rg] / den[s_];
            b1b[swzR(el, s_ >> 3, 32) + (s_ & 7)] = f2b(w);
        }
    __syncthreads();                                       // #3

    f32x4 acc2[2][1]; zacc2(acc2);
    mmg64<4,1>(bA, b1b, acc2, wm, wn, quad, lr);           // Mpart d-half
    f32x4 acc3[2][1]; zacc2(acc3);
    mmg64<4,1>(bA, b1c, acc3, wm, wn, quad, lr);           // KV d-half
    #pragma unroll
    for (int mb = 0; mb < 2; mb++)
        #pragma unroll
        for (int rg = 0; rg < 4; rg++) {
            int d_ = dh*64 + wm*32 + mb*16 + quad*4 + rg;
            int el = wn*16 + lr;
            Mpart[(size_t)c*16384 + (size_t)d_*128 + e0 + el] = acc2[mb][0][rg];
            KV[(size_t)c*16384 + (size_t)d_*128 + e0 + el]    = acc3[mb][0][rg];
        }
}

// fused: exclusive chunk-prefix of KV (-> bf16) and ksum, plus final M_new / z_new
__global__ void k_scan_final(
    const float* __restrict__ KV, const float* __restrict__ ksum,
    const float* __restrict__ M, const float* __restrict__ z,
    const float* __restrict__ Mpart, unsigned short* __restrict__ KVp,
    float* __restrict__ kpre, float* __restrict__ omz)
{
    int idx = blockIdx.x*256 + threadIdx.x;
    if (idx < 32768) {                       // KV scan (per batch)
        int batch = idx >> 14, ed = idx & 16383;
        float a = 0.f;
        #pragma unroll 8
        for (int i = 0; i < CPB; i++) {
            size_t cc = (size_t)(batch*CPB + i);
            KVp[cc*16384 + ed] = f2b(a);
            a += KV[cc*16384 + ed];
        }
    } else if (idx < 33024) {                // ksum scan
        int j = idx - 32768; int batch = j >> 7, d = j & 127;
        float a = 0.f;
        #pragma unroll 8
        for (int i = 0; i < CPB; i++) {
            int cc = batch*CPB + i;
            kpre[cc*128 + d] = a;
            a += ksum[cc*128 + d];
        }
    } else if (idx < 49408) {                // M_new
        int m = idx - 33024;
        float a = M[m];
        #pragma unroll 8
        for (int cc = 0; cc < NCH; cc++) a += Mpart[(size_t)cc*16384 + m];
        omz[m] = a;
    } else if (idx < 49536) {                // z_new
        int d = idx - 49408;
        float a = z[d];
        #pragma unroll 8
        for (int cc = 0; cc < NCH; cc++) a += ksum[cc*128 + d];
        omz[16384 + d] = a;
    }
}

// fused attention per (chunk, e-quarter, s-half): memory-retrieve + inter + intra -> P
// H=0: rows 0..63, causal needs only t<64 (half S + half PV). H=1: rows 64..127, full t.
template<int H>
DI void attn_impl(const unsigned short* Qb, const unsigned short* KVp,
                  const float* kpre, const unsigned short* MbT,
                  const float* z, const float* gate,
                  const unsigned short* Kb, const unsigned short* Vb,
                  unsigned short* P,
                  unsigned short* b0q, unsigned short* b1,
                  unsigned short* bq0, unsigned short* bq1,
                  float* dmem, float* dl, float* rs,
                  int c, int e0, int tid)
{
    const int t0 = c*128;
    const int wave = tid >> 6, lane = tid & 63;
    const int wm = wave >> 1, wn = wave & 1, quad = lane >> 4, lr = lane & 15;
    constexpr int NBT = H ? 4 : 2;     // S col-blocks per wn-half
    constexpr int NKV = H ? 4 : 2;     // PV contraction k-chunks

    if (tid < 64) rs[tid] = 0.f;
    stage_dir<64>(b0q, Qb + (size_t)(t0 + H*64)*Dsz, Dsz, tid);   // Q̃ half (A)
    stage_dir<128>(b1, Kb + (size_t)t0*Dsz, Dsz, tid);            // K̃ full (B for S)
    stage_dir<32>(bq0, MbT + (size_t)e0*128, 128, tid);           // M^T quarter (B)
    stage_T32(bq1, KVp + (size_t)c*16384, 128, e0, tid);          // KVpre quarter (B)
    __syncthreads();                                              // #1

    if (tid < 64) {                                               // dmem = Q̃·z + eps
        float p = 0.f;
        for (int d = 0; d < 128; d++)
            p += b2f(b0q[swzR(tid, d >> 3, 64) + (d & 7)]) * z[d];
        dmem[tid] = p + EPSF;
    } else if (tid < 128) {                                       // dl = Q̃·kpre
        int s_ = tid - 64; float p = 0.f;
        for (int d = 0; d < 128; d++)
            p += b2f(b0q[swzR(s_, d >> 3, 64) + (d & 7)]) * kpre[c*128 + d];
        dl[s_] = p;
    }
    f32x4 accM[2][1]; zacc2(accM);
    mmg64<4,1>(b0q, bq0, accM, wm, wn, quad, lr);                 // mem_num
    f32x4 accN[2][1]; zacc2(accN);
    mmg64<4,1>(b0q, bq1, accN, wm, wn, quad, lr);                 // inter numerator
    f32x4 accS[2][NBT]; zacc2(accS);
    #pragma unroll
    for (int ks = 0; ks < 4; ks++) {                              // S = Q̃ K̃^T
        bf16x8 a[2], b[NBT];
        #pragma unroll
        for (int mb = 0; mb < 2; mb++)
            a[mb] = *(const bf16x8*)&b0q[swzR(wm*32 + mb*16 + lr, ks*4 + quad, 64)];
        #pragma unroll
        for (int nb = 0; nb < NBT; nb++)
            b[nb] = *(const bf16x8*)&b1[swzR(wn*(NBT*16) + nb*16 + lr, ks*4 + quad, 128)];
        #pragma unroll
        for (int mb = 0; mb < 2; mb++)
            #pragma unroll
            for (int nb = 0; nb < NBT; nb++)
                accS[mb][nb] = MFMA(a[mb], b[nb], accS[mb][nb]);
    }
    __syncthreads();                                              // #2

    float g = 1.f / (1.f + expf(-gate[0]));
    f32x4 base[2][1];
    #pragma unroll
    for (int mb = 0; mb < 2; mb++)
        #pragma unroll
        for (int rg = 0; rg < 4; rg++) {
            int s_ = wm*32 + mb*16 + quad*4 + rg;
            base[mb][0][rg] = g * accM[mb][0][rg] / dmem[s_];
        }
    #pragma unroll
    for (int mb = 0; mb < 2; mb++)                 // mask + rowsum + S -> b1 (64-row A)
        #pragma unroll
        for (int rg = 0; rg < 4; rg++) {
            int s_ = wm*32 + mb*16 + quad*4 + rg;  // local row
            int sa = H*64 + s_;                    // absolute row in chunk
            float part = 0.f;
            #pragma unroll
            for (int nb = 0; nb < NBT; nb++) {
                int t_ = wn*(NBT*16) + nb*16 + lr;
                float v = (t_ <= sa) ? accS[mb][nb][rg] : 0.f;
                part += v;
                b1[swzR(s_, t_ >> 3, 64) + (t_ & 7)] = f2b(v);
            }
            #pragma unroll
            for (int m = 1; m < 16; m <<= 1) part += __shfl_xor(part, m, 64);
            if (lr == 0) atomicAdd(&rs[s_], part);
        }
    stage_T32(bq0, Vb + (size_t)t0*Dsz, Dsz, e0, tid);            // V quarter (B)
    __syncthreads();                                              // #3

    f32x4 accV[2][1]; zacc2(accV);
    mmg64<NKV,1>(b1, bq0, accV, wm, wn, quad, lr);                // intra numerator

    #pragma unroll
    for (int mb = 0; mb < 2; mb++)
        #pragma unroll
        for (int rg = 0; rg < 4; rg++) {
            int s_ = wm*32 + mb*16 + quad*4 + rg;
            int el = wn*16 + lr;
            float num = accN[mb][0][rg] + accV[mb][0][rg];
            float dd  = dl[s_] + rs[s_] + EPSF;
            float val = base[mb][0][rg] + (1.f - g) * num / dd;
            P[(size_t)(t0 + H*64 + s_)*Dsz + e0 + el] = f2b(val);
        }
}

__global__ __launch_bounds__(256, 2) void k_attn(
    const unsigned short* __restrict__ Qb, const unsigned short* __restrict__ KVp,
    const float* __restrict__ kpre, const unsigned short* __restrict__ MbT,
    const float* __restrict__ z, const float* __restrict__ gate,
    const unsigned short* __restrict__ Kb, const unsigned short* __restrict__ Vb,
    unsigned short* __restrict__ P)
{
    __shared__ unsigned short b0q[64*128];   // Q̃ half                16KB
    __shared__ unsigned short b1[128*128];   // K̃ full, then S        32KB
    __shared__ unsigned short bq0[32*128];   // Mq then Vq             8KB
    __shared__ unsigned short bq1[32*128];   // KVpq                   8KB
    __shared__ float dmem[64], dl[64], rs[64];
    const int c = blockIdx.x, e0 = blockIdx.y * 32, tid = threadIdx.x;
    if (blockIdx.z == 0)
        attn_impl<0>(Qb, KVp, kpre, MbT, z, gate, Kb, Vb, P,
                     b0q, b1, bq0, bq1, dmem, dl, rs, c, e0, tid);
    else
        attn_impl<1>(Qb, KVp, kpre, MbT, z, gate, Kb, Vb, P,
                     b0q, b1, bq0, bq1, dmem, dl, rs, c, e0, tid);
}

// out = P[8192,128] @ Wo[2048,128]^T, fp32; global_load_lds staging (XOR-permuted)
__global__ __launch_bounds__(256, 2) void k_gemm_out(
    const unsigned short* __restrict__ P, const unsigned short* __restrict__ Wo,
    float* __restrict__ out)
{
    __shared__ unsigned short b0[128*128];   // chunk p = r*16 + (kc^(r&15))
    __shared__ unsigned short b1[128*128];
    const int tid = threadIdx.x;
    const int row0 = blockIdx.x*128, n0 = blockIdx.y*128;
    const int wave = tid >> 6, lane = tid & 63;
    const int wm = wave >> 1, wn = wave & 1, quad = lane >> 4, lr = lane & 15;

    #pragma unroll
    for (int i = 0; i < 8; i++) {
        int p = tid + i*256; int r = p >> 4; int kc = (p & 15) ^ (r & 15);
        gll16(P + (size_t)(row0 + r)*Dsz + kc*8, &b0[p*8]);
    }
    #pragma unroll
    for (int i = 0; i < 8; i++) {
        int p = tid + i*256; int r = p >> 4; int kc = (p & 15) ^ (r & 15);
        gll16(Wo + (size_t)(n0 + r)*Dsz + kc*8, &b1[p*8]);
    }
    __syncthreads();

    f32x4 acc[4][4]; zaccg(acc);
    #pragma unroll
    for (int ks = 0; ks < 4; ks++) {
        bf16x8 a[4], b[4];
        #pragma unroll
        for (int mb = 0; mb < 4; mb++) {
            int r = wm*64 + mb*16 + lr;
            a[mb] = *(const bf16x8*)&b0[(r*16 + ((ks*4 + quad) ^ (r & 15)))*8];
        }
        #pragma unroll
        for (int nb = 0; nb < 4; nb++) {
            int r = wn*64 + nb*16 + lr;
            b[nb] = *(const bf16x8*)&b1[(r*16 + ((ks*4 + quad) ^ (r & 15)))*8];
        }
        #pragma unroll
        for (int mb = 0; mb < 4; mb++)
            #pragma unroll
            for (int nb = 0; nb < 4; nb++)
                acc[mb][nb] = MFMA(a[mb], b[nb], acc[mb][nb]);
    }
    #pragma unroll
    for (int mb = 0; mb < 4; mb++)
        #pragma unroll
        for (int nb = 0; nb < 4; nb++)
            #pragma unroll
            for (int rg = 0; rg < 4; rg++) {
                int s_ = wm*64 + mb*16 + quad*4 + rg;
                int e_ = wn*64 + nb*16 + lr;
                out[(size_t)(row0 + s_)*Hsz + n0 + e_] = acc[mb][nb][rg];
            }
}

// ---------------- launcher ----------------
extern "C" void kernel_launch(void* const* d_in, const int* in_sizes, int n_in,
                              void* d_out, int out_size, void* d_ws, size_t ws_size,
                              hipStream_t stream)
{
    const float* X    = (const float*)d_in[0];
    const float* wq   = (const float*)d_in[1];
    const float* wk   = (const float*)d_in[2];
    const float* wv   = (const float*)d_in[3];
    const float* wo   = (const float*)d_in[4];
    const float* gate = (const float*)d_in[5];
    const float* M    = (const float*)d_in[6];
    const float* z    = (const float*)d_in[7];

    char* ws = (char*)d_ws;
    unsigned short* Wfull = (unsigned short*)(ws + WQKV_OFF);
    unsigned short* Wo_b  = (unsigned short*)(ws + WO_OFF);
    unsigned short* MbT   = (unsigned short*)(ws + MBT_OFF);
    unsigned short* Qb    = (unsigned short*)(ws + QB_OFF);
    unsigned short* Kb    = (unsigned short*)(ws + KB_OFF);
    unsigned short* Vb    = (unsigned short*)(ws + VB_OFF);
    unsigned short* Pb    = (unsigned short*)(ws + PB_OFF);
    unsigned short* AccB  = (unsigned short*)(ws + ACC_OFF);
    float* KV    = (float*)(ws + KV_OFF);
    unsigned short* KVp = (unsigned short*)(ws + KVP_OFF);
    float* Mpart = (float*)(ws + MPART_OFF);
    float* ksum  = (float*)(ws + KSUM_OFF);
    float* kpre  = (float*)(ws + KPRE_OFF);

    float* outp   = (float*)d_out;
    float* out_mz = outp + (size_t)Nrow*Hsz;

    k_cvt_w<<<((4*WN + 16384)/4 + 255)/256, 256, 0, stream>>>(wq, wk, wv, wo, M, Wfull, MbT);
    k_gemm_qkv<<<dim3(Nrow/128, 4), 512, 0, stream>>>(X, Wfull, AccB);
    k_qkv_epi<<<(3*Nrow*16)/256, 256, 0, stream>>>(AccB, Qb, Kb, Vb);
    k_delta_kv<<<dim3(NCH, 4, 2), 256, 0, stream>>>(Kb, Vb, MbT, z, KV, ksum, Mpart);
    k_scan_final<<<194, 256, 0, stream>>>(KV, ksum, M, z, Mpart, KVp, kpre, out_mz);
    k_attn<<<dim3(NCH, 4, 2), 256, 0, stream>>>(Qb, KVp, kpre, MbT, z, gate, Kb, Vb, Pb);
    k_gemm_out<<<dim3(Nrow/128, Hsz/128), 256, 0, stream>>>(Pb, Wo_b, outp);
}

// Round 3
// 178.378 us; speedup vs baseline: 1.0103x; 1.0013x over previous
//
#include <hip/hip_runtime.h>
#include <hip/hip_bf16.h>
#include <math.h>

#define DI __device__ __forceinline__

typedef __bf16 bf16x8 __attribute__((ext_vector_type(8)));
typedef float  f32x4  __attribute__((ext_vector_type(4)));

static constexpr int   Bsz  = 2, Ssz = 4096, Hsz = 2048, Dsz = 128;
static constexpr int   Nrow = Bsz * Ssz;     // 8192
static constexpr int   NCH  = Nrow / 128;    // 64 chunks
static constexpr int   CPB  = Ssz / 128;     // 32 chunks per batch
static constexpr int   WN   = Dsz * Hsz;     // 262144
static constexpr float EPSF = 1e-6f;

// ---------------- workspace layout (bytes) ----------------
static constexpr size_t WQKV_OFF = 0;                            // bf16 [384][2048]
static constexpr size_t WO_OFF   = (size_t)3*WN*2;               // bf16 [2048][128]
static constexpr size_t MB_OFF   = WO_OFF + (size_t)WN*2;        // bf16 [128][128] (cvt spill)
static constexpr size_t MBT_OFF  = MB_OFF + 32768;               // bf16 M^T [128][128]
static constexpr size_t QB_OFF   = MBT_OFF + 32768;              // bf16 [8192][128]
static constexpr size_t KB_OFF   = QB_OFF + (size_t)Nrow*Dsz*2;
static constexpr size_t VB_OFF   = KB_OFF + (size_t)Nrow*Dsz*2;
static constexpr size_t PB_OFF   = VB_OFF + (size_t)Nrow*Dsz*2;
static constexpr size_t ACC_OFF  = PB_OFF + (size_t)Nrow*Dsz*2;  // bf16 [4][3][8192][128] = 25.2MB
// --- aliased into ACC region (dead after k_qkv_epi) ---
static constexpr size_t KV_OFF   = ACC_OFF;                      // f32 [64][128d][128e] 4MB
static constexpr size_t KVP_OFF  = ACC_OFF + (size_t)4*1024*1024;// bf16 [64][128d][128e] 2MB
static constexpr size_t MPART_OFF= ACC_OFF + (size_t)6*1024*1024;// f32 [64][128][128] 4MB
static constexpr size_t KSUM_OFF = ACC_OFF + (size_t)10*1024*1024;// f32 [64][128]
static constexpr size_t KPRE_OFF = KSUM_OFF + 32768;             // f32 [64][128]

// ---------------- helpers ----------------
DI float b2f(unsigned short u) {
    union { float f; unsigned int i; } x; x.i = ((unsigned int)u) << 16; return x.f;
}
DI unsigned short f2b(float f) {
    __bf16 h = (__bf16)f; return __builtin_bit_cast(unsigned short, h);
}
DI float sig_elu(float x) { return x > 0.f ? x + 1.f : expf(x); }

DI f32x4 MFMA(bf16x8 a, bf16x8 b, f32x4 c) {
    return __builtin_amdgcn_mfma_f32_16x16x32_bf16(a, b, c, 0, 0, 0);
}
template<int NB>
DI void zaccg(f32x4 (&acc)[4][NB]) {
    f32x4 zz = {0.f, 0.f, 0.f, 0.f};
    #pragma unroll
    for (int i = 0; i < 4; i++)
        #pragma unroll
        for (int j = 0; j < NB; j++) acc[i][j] = zz;
}
template<int NB>
DI void zacc2(f32x4 (&acc)[2][NB]) {
    f32x4 zz = {0.f, 0.f, 0.f, 0.f};
    #pragma unroll
    for (int i = 0; i < 2; i++)
        #pragma unroll
        for (int j = 0; j < NB; j++) acc[i][j] = zz;
}

// async 16B global -> LDS (DMA, bypasses VGPRs). LDS dst = wave-uniform base + lane*16.
DI void gll16(const void* g, void* l) {
    __builtin_amdgcn_global_load_lds((const __attribute__((address_space(1))) void*)g,
                                     (__attribute__((address_space(3))) void*)l, 16, 0, 0);
}

// swizzled chunk offset (ushorts) of 8-elem chunk (r, kc) in a VALU-staged operand
// tile with R rows (XOR banking)
DI int swzR(int r, int kc, int R) { return (kc*R + (r ^ (kc & 7))) * 8; }

// generic matmul out of swzR-layout LDS: A 128 rows, B NB*32 rows
template<int NKS, int NB>
DI void mmg(const unsigned short* A, const unsigned short* Bm, f32x4 (&acc)[4][NB],
            int wm, int wn, int quad, int lr) {
    #pragma unroll
    for (int ks = 0; ks < NKS; ks++) {
        bf16x8 a[4], b[NB];
        #pragma unroll
        for (int mb = 0; mb < 4; mb++)
            a[mb] = *(const bf16x8*)&A[swzR(wm*64 + mb*16 + lr, ks*4 + quad, 128)];
        #pragma unroll
        for (int nb = 0; nb < NB; nb++)
            b[nb] = *(const bf16x8*)&Bm[swzR(wn*(NB*16) + nb*16 + lr, ks*4 + quad, NB*32)];
        #pragma unroll
        for (int mb = 0; mb < 4; mb++)
            #pragma unroll
            for (int nb = 0; nb < NB; nb++)
                acc[mb][nb] = MFMA(a[mb], b[nb], acc[mb][nb]);
    }
}

// matmul with 64-row A tile: rows = wm*32 + mb*16, mb<2
template<int NKS, int NB>
DI void mmg64(const unsigned short* A, const unsigned short* Bm, f32x4 (&acc)[2][NB],
              int wm, int wn, int quad, int lr) {
    #pragma unroll
    for (int ks = 0; ks < NKS; ks++) {
        bf16x8 a[2], b[NB];
        #pragma unroll
        for (int mb = 0; mb < 2; mb++)
            a[mb] = *(const bf16x8*)&A[swzR(wm*32 + mb*16 + lr, ks*4 + quad, 64)];
        #pragma unroll
        for (int nb = 0; nb < NB; nb++)
            b[nb] = *(const bf16x8*)&Bm[swzR(wn*(NB*16) + nb*16 + lr, ks*4 + quad, NB*32)];
        #pragma unroll
        for (int mb = 0; mb < 2; mb++)
            #pragma unroll
            for (int nb = 0; nb < NB; nb++)
                acc[mb][nb] = MFMA(a[mb], b[nb], acc[mb][nb]);
    }
}

// row-major [R][128] bf16 tile -> swzR operand layout (VALU path)
template<int R>
DI void stage_dir(unsigned short* dst, const unsigned short* src, int src_ld, int tid) {
    #pragma unroll
    for (int i = 0; i < R/16; i++) {
        int s = tid + i*256; int r = s >> 4, kc = s & 15;
        *(uint4*)&dst[swzR(r, kc, R)] = *(const uint4*)(src + (size_t)r*src_ld + kc*8);
    }
}

// transposed staging (full 128): operand elem (r=col, k=row) <- src[row][col]
DI void stage_T128(unsigned short* dst, const unsigned short* src, int src_ld, int tid) {
    #pragma unroll
    for (int i = 0; i < 8; i++) {
        int s = tid + i*256;
        int rw = (s & 15) + ((s >> 8) << 4);
        int c0 = ((s >> 4) & 15) * 8;
        unsigned short tmp[8];
        *(uint4*)tmp = *(const uint4*)(src + (size_t)rw*src_ld + c0);
        #pragma unroll
        for (int j = 0; j < 8; j++)
            dst[swzR(c0 + j, rw >> 3, 128) + (rw & 7)] = tmp[j];
    }
}

// transposed staging into 64-row operand: elem (r=col-colOff, k=row) <- src[row][colOff+col]
DI void stage_T64(unsigned short* dst, const unsigned short* src, int src_ld, int colOff, int tid) {
    #pragma unroll
    for (int i = 0; i < 4; i++) {
        int s = tid + i*256;                 // 0..1023
        int rw = s >> 3;                     // row 0..127
        int c0 = (s & 7) * 8;                // col 0..56
        unsigned short tmp[8];
        *(uint4*)tmp = *(const uint4*)(src + (size_t)rw*src_ld + colOff + c0);
        #pragma unroll
        for (int j = 0; j < 8; j++)
            dst[swzR(c0 + j, rw >> 3, 64) + (rw & 7)] = tmp[j];
    }
}

// transposed staging into 32-row operand: elem (r=col-colOff, k=row) <- src[row][colOff+col]
DI void stage_T32(unsigned short* dst, const unsigned short* src, int src_ld, int colOff, int tid) {
    #pragma unroll
    for (int i = 0; i < 2; i++) {
        int s = tid + i*256;                     // 0..511
        int rw = (s & 15) + ((s >> 6) << 4);     // 0..127
        int c0 = ((s >> 4) & 3) * 8;             // 0..24
        unsigned short tmp[8];
        *(uint4*)tmp = *(const uint4*)(src + (size_t)rw*src_ld + colOff + c0);
        #pragma unroll
        for (int j = 0; j < 8; j++)
            dst[swzR(c0 + j, rw >> 3, 32) + (rw & 7)] = tmp[j];
    }
}

// ---------------- kernels ----------------

// fused weight conversion: wq|wk|wv -> Wqkv, wo -> Wo, M -> (spill) and MbT
__global__ void k_cvt_w(const float* __restrict__ wq, const float* __restrict__ wk,
                        const float* __restrict__ wv, const float* __restrict__ wo,
                        const float* __restrict__ M, unsigned short* __restrict__ dst,
                        unsigned short* __restrict__ MbT)
{
    int gid = blockIdx.x*256 + threadIdx.x;
    if (gid >= (4*WN + 16384)/4) return;
    int e = gid*4;
    const float* src; int rel;
    if      (e < WN)     { src = wq; rel = e; }
    else if (e < 2*WN)   { src = wk; rel = e - WN; }
    else if (e < 3*WN)   { src = wv; rel = e - 2*WN; }
    else if (e < 4*WN)   { src = wo; rel = e - 3*WN; }
    else                 { src = M;  rel = e - 4*WN; }
    float4 v = *(const float4*)(src + rel);
    const float* vf = (const float*)&v;
    unsigned short o[4];
    #pragma unroll
    for (int j = 0; j < 4; j++) o[j] = f2b(vf[j]);
    *(uint2*)&dst[e] = *(const uint2*)o;
    if (e >= 4*WN) {
        #pragma unroll
        for (int j = 0; j < 4; j++) {
            int d = (rel + j) >> 7, ee = (rel + j) & 127;
            MbT[ee*128 + d] = o[j];
        }
    }
}

// QKV projection: X[8192,2048]fp32 @ Wqkv[384,2048]^T, single X pass.
// 64-row tiles x full 384 cols, 256 threads (4 waves), grid (128 rows, 4 ksplit)
// = 512 blocks -> 2 independent blocks/CU (LDS 56KB, VGPR budget 256 at 2 w/SIMD).
// Block pairs hide each other's per-K-step barrier drains.
__global__ __launch_bounds__(256, 2) void k_gemm_qkv(
    const float* __restrict__ X, const unsigned short* __restrict__ W,
    unsigned short* __restrict__ AccB)
{
    __shared__ unsigned short lA[64*64];    // bf16, slot p = r*8 + (kc^(r&7))   8KB
    __shared__ unsigned short lB[384*64];   // bf16, same swizzle               48KB
    const int tid = threadIdx.x;            // 0..255
    const int row0 = blockIdx.x * 64;
    const int kb   = blockIdx.y * 512;      // K-split of 4
    const int wave = tid >> 6, lane = tid & 63;
    const int quad = lane >> 4, lr = lane & 15;

    // A staging: 512 chunks of 8 fp32 -> 2 chunks/thread
    const int cA0 = tid, cA1 = tid + 256;
    const int rA0 = cA0 >> 3, kA0 = cA0 & 7;
    const int rA1 = cA1 >> 3, kA1 = cA1 & 7;
    const float* pA0 = X + (size_t)(row0 + rA0)*Hsz + kA0*8;
    const float* pA1 = X + (size_t)(row0 + rA1)*Hsz + kA1*8;
    unsigned short* wA0 = &lA[(rA0*8 + (kA0 ^ (rA0 & 7)))*8];
    unsigned short* wA1 = &lA[(rA1*8 + (kA1 ^ (rA1 & 7)))*8];

    f32x4 acc[4][6]; zaccg(acc);

    // prologue: A register loads for first K-step
    float4 a00 = *(const float4*)(pA0 + kb);
    float4 a01 = *(const float4*)(pA0 + kb + 4);
    float4 a10 = *(const float4*)(pA1 + kb);
    float4 a11 = *(const float4*)(pA1 + kb + 4);

    for (int kt = kb; kt < kb + 512; kt += 64) {
        // B: 3072 chunks of 8 bf16 -> 12 DMA/thread (source XOR-permuted)
        #pragma unroll
        for (int i = 0; i < 12; i++) {
            int p = tid + i*256; int r = p >> 3; int kc = (p & 7) ^ (r & 7);
            gll16(W + (size_t)r*Hsz + kt + kc*8, &lB[p*8]);
        }
        // A: cvt staged regs -> bf16 swizzled LDS
        {
            unsigned short o[8];
            const float* f0 = (const float*)&a00; const float* f1 = (const float*)&a01;
            #pragma unroll
            for (int j = 0; j < 4; j++) { o[j] = f2b(f0[j]); o[4+j] = f2b(f1[j]); }
            *(uint4*)wA0 = *(const uint4*)o;
            const float* f2 = (const float*)&a10; const float* f3 = (const float*)&a11;
            #pragma unroll
            for (int j = 0; j < 4; j++) { o[j] = f2b(f2[j]); o[4+j] = f2b(f3[j]); }
            *(uint4*)wA1 = *(const uint4*)o;
        }
        __syncthreads();
        // prefetch next K-step's A registers; streams under the MFMA phase
        if (kt + 64 < kb + 512) {
            a00 = *(const float4*)(pA0 + kt + 64);
            a01 = *(const float4*)(pA0 + kt + 64 + 4);
            a10 = *(const float4*)(pA1 + kt + 64);
            a11 = *(const float4*)(pA1 + kt + 64 + 4);
        }
        #pragma unroll
        for (int ks = 0; ks < 2; ks++) {
            bf16x8 a[4], b[6];
            #pragma unroll
            for (int mb = 0; mb < 4; mb++) {
                int r = mb*16 + lr;
                int c = (ks*4 + quad) ^ (r & 7);
                a[mb] = *(const bf16x8*)&lA[(r*8 + c)*8];
            }
            #pragma unroll
            for (int nb = 0; nb < 6; nb++) {
                int r = wave*96 + nb*16 + lr;
                int c = (ks*4 + quad) ^ (r & 7);
                b[nb] = *(const bf16x8*)&lB[(r*8 + c)*8];
            }
            #pragma unroll
            for (int mb = 0; mb < 4; mb++)
                #pragma unroll
                for (int nb = 0; nb < 6; nb++)
                    acc[mb][nb] = MFMA(a[mb], b[nb], acc[mb][nb]);
        }
        __syncthreads();
    }

    // write partials: slab (ksplit*3 + ct), same layout -> epi unchanged
    unsigned short* base = AccB + (size_t)blockIdx.y * 3 * Nrow * 128;
    #pragma unroll
    for (int mb = 0; mb < 4; mb++)
        #pragma unroll
        for (int nb = 0; nb < 6; nb++)
            #pragma unroll
            for (int rg = 0; rg < 4; rg++) {
                int s_ = mb*16 + quad*4 + rg;
                int n  = wave*96 + nb*16 + lr;         // 0..383
                int ct = n >> 7, e_ = n & 127;
                base[(size_t)ct*Nrow*128 + (size_t)(row0 + s_)*128 + e_] =
                    f2b(acc[mb][nb][rg]);
            }
}

// epilogue: sum 4 bf16 partial slabs -> sigma (q,k) -> bf16 Q/K/V
__global__ void k_qkv_epi(const unsigned short* __restrict__ AccB,
                          unsigned short* __restrict__ Qb,
                          unsigned short* __restrict__ Kb, unsigned short* __restrict__ Vb)
{
    int gid = blockIdx.x*256 + threadIdx.x;      // 393216 threads, 8 elems each
    int ct = gid / (Nrow*16);
    int off = (gid - ct*Nrow*16) * 8;
    float vs[8];
    #pragma unroll
    for (int j = 0; j < 8; j++) vs[j] = 0.f;
    #pragma unroll
    for (int s = 0; s < 4; s++) {
        uint4 u = *(const uint4*)&AccB[((size_t)s*3 + ct)*Nrow*128 + off];
        const unsigned short* us = (const unsigned short*)&u;
        #pragma unroll
        for (int j = 0; j < 8; j++) vs[j] += b2f(us[j]);
    }
    unsigned short o[8];
    if (ct < 2) {
        #pragma unroll
        for (int j = 0; j < 8; j++) o[j] = f2b(sig_elu(vs[j]));
    } else {
        #pragma unroll
        for (int j = 0; j < 8; j++) o[j] = f2b(vs[j]);
    }
    unsigned short* dst = (ct == 0) ? Qb : (ct == 1 ? Kb : Vb);
    *(uint4*)&dst[off] = *(const uint4*)o;
}

// per (chunk, e-quarter, d-half): vret=(K̃M)/(K̃·z+eps); Mpart[dh,:][eq]=K̃^T(V-vret);
// KV[dh,:][eq]=K̃^T V; ksum (eq==0,dh==0 only). 512 blocks -> 2 blocks/CU.
__global__ __launch_bounds__(256, 2) void k_delta_kv(
    const unsigned short* __restrict__ Kb, const unsigned short* __restrict__ Vb,
    const unsigned short* __restrict__ MbT, const float* __restrict__ z,
    float* __restrict__ KV, float* __restrict__ ksum, float* __restrict__ Mpart)
{
    __shared__ unsigned short b0[128*128];   // K̃ (dir, full)        32KB
    __shared__ unsigned short bA[64*128];    // K̃^T d-half (A)       16KB
    __shared__ unsigned short b1a[32*128];   // M^T quarter, B        8KB
    __shared__ unsigned short b1b[32*128];   // W = V - vret, B       8KB
    __shared__ unsigned short b1c[32*128];   // V quarter, B          8KB
    __shared__ float den[128];
    const int tid = threadIdx.x;
    const int c = blockIdx.x, t0 = c*128;
    const int e0 = blockIdx.y * 32;
    const int dh = blockIdx.z;               // d-half 0/1
    const int wave = tid >> 6, lane = tid & 63;
    const int wm = wave >> 1, wn = wave & 1, quad = lane >> 4, lr = lane & 15;

    stage_dir<128>(b0, Kb + (size_t)t0*Dsz, Dsz, tid);     // K̃ (A for vret)
    stage_T64(bA, Kb + (size_t)t0*Dsz, Dsz, dh*64, tid);   // K̃^T d-half
    stage_dir<32>(b1a, MbT + (size_t)e0*128, 128, tid);    // M^T quarter (B)
    stage_T32(b1c, Vb + (size_t)t0*Dsz, Dsz, e0, tid);     // V quarter (B: (el,t))
    __syncthreads();                                       // #1

    f32x4 acc1[4][1]; zaccg(acc1);
    mmg<4,1>(b0, b1a, acc1, wm, wn, quad, lr);             // vret_num[t][el] (full t)

    if (tid < 128) {                                       // den[t] = K̃[t]·z + eps
        float p = 0.f;
        for (int d = 0; d < 128; d++)
            p += b2f(b0[swzR(tid, d >> 3, 128) + (d & 7)]) * z[d];
        den[tid] = p + EPSF;
        if (e0 == 0 && dh == 0) {                          // ksum[d] = sum_t K̃[t][d]
            float q = 0.f;
            for (int t = 0; t < 128; t++)
                q += b2f(b0[swzR(t, tid >> 3, 128) + (tid & 7)]);
            ksum[(size_t)c*128 + tid] = q;
        }
    }
    __syncthreads();                                       // #2 (den ready)

    #pragma unroll
    for (int mb = 0; mb < 4; mb++)                         // b1b <- W = V - vret
        #pragma unroll
        for (int rg = 0; rg < 4; rg++) {
            int s_ = wm*64 + mb*16 + quad*4 + rg;
            int el = wn*16 + lr;
            float v = b2f(Vb[(size_t)(t0 + s_)*Dsz + e0 + el]);
            float w = v - acc1[mb][0][rg] / den[s_];
            b1b[swzR(el, s_ >> 3, 32) + (s_ & 7)] = f2b(w);
        }
    __syncthreads();                                       // #3

    f32x4 acc2[2][1]; zacc2(acc2);
    mmg64<4,1>(bA, b1b, acc2, wm, wn, quad, lr);           // Mpart d-half
    f32x4 acc3[2][1]; zacc2(acc3);
    mmg64<4,1>(bA, b1c, acc3, wm, wn, quad, lr);           // KV d-half
    #pragma unroll
    for (int mb = 0; mb < 2; mb++)
        #pragma unroll
        for (int rg = 0; rg < 4; rg++) {
            int d_ = dh*64 + wm*32 + mb*16 + quad*4 + rg;
            int el = wn*16 + lr;
            Mpart[(size_t)c*16384 + (size_t)d_*128 + e0 + el] = acc2[mb][0][rg];
            KV[(size_t)c*16384 + (size_t)d_*128 + e0 + el]    = acc3[mb][0][rg];
        }
}

// fused: exclusive chunk-prefix of KV (-> bf16) and ksum, plus final M_new / z_new
__global__ void k_scan_final(
    const float* __restrict__ KV, const float* __restrict__ ksum,
    const float* __restrict__ M, const float* __restrict__ z,
    const float* __restrict__ Mpart, unsigned short* __restrict__ KVp,
    float* __restrict__ kpre, float* __restrict__ omz)
{
    int idx = blockIdx.x*256 + threadIdx.x;
    if (idx < 32768) {                       // KV scan (per batch)
        int batch = idx >> 14, ed = idx & 16383;
        float a = 0.f;
        #pragma unroll 8
        for (int i = 0; i < CPB; i++) {
            size_t cc = (size_t)(batch*CPB + i);
            KVp[cc*16384 + ed] = f2b(a);
            a += KV[cc*16384 + ed];
        }
    } else if (idx < 33024) {                // ksum scan
        int j = idx - 32768; int batch = j >> 7, d = j & 127;
        float a = 0.f;
        #pragma unroll 8
        for (int i = 0; i < CPB; i++) {
            int cc = batch*CPB + i;
            kpre[cc*128 + d] = a;
            a += ksum[cc*128 + d];
        }
    } else if (idx < 49408) {                // M_new
        int m = idx - 33024;
        float a = M[m];
        #pragma unroll 8
        for (int cc = 0; cc < NCH; cc++) a += Mpart[(size_t)cc*16384 + m];
        omz[m] = a;
    } else if (idx < 49536) {                // z_new
        int d = idx - 49408;
        float a = z[d];
        #pragma unroll 8
        for (int cc = 0; cc < NCH; cc++) a += ksum[cc*128 + d];
        omz[16384 + d] = a;
    }
}

// fused attention per (chunk, e-quarter, s-half): memory-retrieve + inter + intra -> P
// H=0: rows 0..63, causal needs only t<64 (half S + half PV). H=1: rows 64..127, full t.
template<int H>
DI void attn_impl(const unsigned short* Qb, const unsigned short* KVp,
                  const float* kpre, const unsigned short* MbT,
                  const float* z, const float* gate,
                  const unsigned short* Kb, const unsigned short* Vb,
                  unsigned short* P,
                  unsigned short* b0q, unsigned short* b1,
                  unsigned short* bq0, unsigned short* bq1,
                  float* dmem, float* dl, float* rs,
                  int c, int e0, int tid)
{
    const int t0 = c*128;
    const int wave = tid >> 6, lane = tid & 63;
    const int wm = wave >> 1, wn = wave & 1, quad = lane >> 4, lr = lane & 15;
    constexpr int NBT = H ? 4 : 2;     // S col-blocks per wn-half
    constexpr int NKV = H ? 4 : 2;     // PV contraction k-chunks

    if (tid < 64) rs[tid] = 0.f;
    stage_dir<64>(b0q, Qb + (size_t)(t0 + H*64)*Dsz, Dsz, tid);   // Q̃ half (A)
    stage_dir<128>(b1, Kb + (size_t)t0*Dsz, Dsz, tid);            // K̃ full (B for S)
    stage_dir<32>(bq0, MbT + (size_t)e0*128, 128, tid);           // M^T quarter (B)
    stage_T32(bq1, KVp + (size_t)c*16384, 128, e0, tid);          // KVpre quarter (B)
    __syncthreads();                                              // #1

    if (tid < 64) {                                               // dmem = Q̃·z + eps
        float p = 0.f;
        for (int d = 0; d < 128; d++)
            p += b2f(b0q[swzR(tid, d >> 3, 64) + (d & 7)]) * z[d];
        dmem[tid] = p + EPSF;
    } else if (tid < 128) {                                       // dl = Q̃·kpre
        int s_ = tid - 64; float p = 0.f;
        for (int d = 0; d < 128; d++)
            p += b2f(b0q[swzR(s_, d >> 3, 64) + (d & 7)]) * kpre[c*128 + d];
        dl[s_] = p;
    }
    f32x4 accM[2][1]; zacc2(accM);
    mmg64<4,1>(b0q, bq0, accM, wm, wn, quad, lr);                 // mem_num
    f32x4 accN[2][1]; zacc2(accN);
    mmg64<4,1>(b0q, bq1, accN, wm, wn, quad, lr);                 // inter numerator
    f32x4 accS[2][NBT]; zacc2(accS);
    #pragma unroll
    for (int ks = 0; ks < 4; ks++) {                              // S = Q̃ K̃^T
        bf16x8 a[2], b[NBT];
        #pragma unroll
        for (int mb = 0; mb < 2; mb++)
            a[mb] = *(const bf16x8*)&b0q[swzR(wm*32 + mb*16 + lr, ks*4 + quad, 64)];
        #pragma unroll
        for (int nb = 0; nb < NBT; nb++)
            b[nb] = *(const bf16x8*)&b1[swzR(wn*(NBT*16) + nb*16 + lr, ks*4 + quad, 128)];
        #pragma unroll
        for (int mb = 0; mb < 2; mb++)
            #pragma unroll
            for (int nb = 0; nb < NBT; nb++)
                accS[mb][nb] = MFMA(a[mb], b[nb], accS[mb][nb]);
    }
    __syncthreads();                                              // #2

    float g = 1.f / (1.f + expf(-gate[0]));
    f32x4 base[2][1];
    #pragma unroll
    for (int mb = 0; mb < 2; mb++)
        #pragma unroll
        for (int rg = 0; rg < 4; rg++) {
            int s_ = wm*32 + mb*16 + quad*4 + rg;
            base[mb][0][rg] = g * accM[mb][0][rg] / dmem[s_];
        }
    #pragma unroll
    for (int mb = 0; mb < 2; mb++)                 // mask + rowsum + S -> b1 (64-row A)
        #pragma unroll
        for (int rg = 0; rg < 4; rg++) {
            int s_ = wm*32 + mb*16 + quad*4 + rg;  // local row
            int sa = H*64 + s_;                    // absolute row in chunk
            float part = 0.f;
            #pragma unroll
            for (int nb = 0; nb < NBT; nb++) {
                int t_ = wn*(NBT*16) + nb*16 + lr;
                float v = (t_ <= sa) ? accS[mb][nb][rg] : 0.f;
                part += v;
                b1[swzR(s_, t_ >> 3, 64) + (t_ & 7)] = f2b(v);
            }
            #pragma unroll
            for (int m = 1; m < 16; m <<= 1) part += __shfl_xor(part, m, 64);
            if (lr == 0) atomicAdd(&rs[s_], part);
        }
    stage_T32(bq0, Vb + (size_t)t0*Dsz, Dsz, e0, tid);            // V quarter (B)
    __syncthreads();                                              // #3

    f32x4 accV[2][1]; zacc2(accV);
    mmg64<NKV,1>(b1, bq0, accV, wm, wn, quad, lr);                // intra numerator

    #pragma unroll
    for (int mb = 0; mb < 2; mb++)
        #pragma unroll
        for (int rg = 0; rg < 4; rg++) {
            int s_ = wm*32 + mb*16 + quad*4 + rg;
            int el = wn*16 + lr;
            float num = accN[mb][0][rg] + accV[mb][0][rg];
            float dd  = dl[s_] + rs[s_] + EPSF;
            float val = base[mb][0][rg] + (1.f - g) * num / dd;
            P[(size_t)(t0 + H*64 + s_)*Dsz + e0 + el] = f2b(val);
        }
}

__global__ __launch_bounds__(256, 2) void k_attn(
    const unsigned short* __restrict__ Qb, const unsigned short* __restrict__ KVp,
    const float* __restrict__ kpre, const unsigned short* __restrict__ MbT,
    const float* __restrict__ z, const float* __restrict__ gate,
    const unsigned short* __restrict__ Kb, const unsigned short* __restrict__ Vb,
    unsigned short* __restrict__ P)
{
    __shared__ unsigned short b0q[64*128];   // Q̃ half                16KB
    __shared__ unsigned short b1[128*128];   // K̃ full, then S        32KB
    __shared__ unsigned short bq0[32*128];   // Mq then Vq             8KB
    __shared__ unsigned short bq1[32*128];   // KVpq                   8KB
    __shared__ float dmem[64], dl[64], rs[64];
    const int c = blockIdx.x, e0 = blockIdx.y * 32, tid = threadIdx.x;
    if (blockIdx.z == 0)
        attn_impl<0>(Qb, KVp, kpre, MbT, z, gate, Kb, Vb, P,
                     b0q, b1, bq0, bq1, dmem, dl, rs, c, e0, tid);
    else
        attn_impl<1>(Qb, KVp, kpre, MbT, z, gate, Kb, Vb, P,
                     b0q, b1, bq0, bq1, dmem, dl, rs, c, e0, tid);
}

// out = P[8192,128] @ Wo[2048,128]^T, fp32; global_load_lds staging (XOR-permuted)
__global__ __launch_bounds__(256, 2) void k_gemm_out(
    const unsigned short* __restrict__ P, const unsigned short* __restrict__ Wo,
    float* __restrict__ out)
{
    __shared__ unsigned short b0[128*128];   // chunk p = r*16 + (kc^(r&15))
    __shared__ unsigned short b1[128*128];
    const int tid = threadIdx.x;
    const int row0 = blockIdx.x*128, n0 = blockIdx.y*128;
    const int wave = tid >> 6, lane = tid & 63;
    const int wm = wave >> 1, wn = wave & 1, quad = lane >> 4, lr = lane & 15;

    #pragma unroll
    for (int i = 0; i < 8; i++) {
        int p = tid + i*256; int r = p >> 4; int kc = (p & 15) ^ (r & 15);
        gll16(P + (size_t)(row0 + r)*Dsz + kc*8, &b0[p*8]);
    }
    #pragma unroll
    for (int i = 0; i < 8; i++) {
        int p = tid + i*256; int r = p >> 4; int kc = (p & 15) ^ (r & 15);
        gll16(Wo + (size_t)(n0 + r)*Dsz + kc*8, &b1[p*8]);
    }
    __syncthreads();

    f32x4 acc[4][4]; zaccg(acc);
    #pragma unroll
    for (int ks = 0; ks < 4; ks++) {
        bf16x8 a[4], b[4];
        #pragma unroll
        for (int mb = 0; mb < 4; mb++) {
            int r = wm*64 + mb*16 + lr;
            a[mb] = *(const bf16x8*)&b0[(r*16 + ((ks*4 + quad) ^ (r & 15)))*8];
        }
        #pragma unroll
        for (int nb = 0; nb < 4; nb++) {
            int r = wn*64 + nb*16 + lr;
            b[nb] = *(const bf16x8*)&b1[(r*16 + ((ks*4 + quad) ^ (r & 15)))*8];
        }
        #pragma unroll
        for (int mb = 0; mb < 4; mb++)
            #pragma unroll
            for (int nb = 0; nb < 4; nb++)
                acc[mb][nb] = MFMA(a[mb], b[nb], acc[mb][nb]);
    }
    #pragma unroll
    for (int mb = 0; mb < 4; mb++)
        #pragma unroll
        for (int nb = 0; nb < 4; nb++)
            #pragma unroll
            for (int rg = 0; rg < 4; rg++) {
                int s_ = wm*64 + mb*16 + quad*4 + rg;
                int e_ = wn*64 + nb*16 + lr;
                out[(size_t)(row0 + s_)*Hsz + n0 + e_] = acc[mb][nb][rg];
            }
}

// ---------------- launcher ----------------
extern "C" void kernel_launch(void* const* d_in, const int* in_sizes, int n_in,
                              void* d_out, int out_size, void* d_ws, size_t ws_size,
                              hipStream_t stream)
{
    const float* X    = (const float*)d_in[0];
    const float* wq   = (const float*)d_in[1];
    const float* wk   = (const float*)d_in[2];
    const float* wv   = (const float*)d_in[3];
    const float* wo   = (const float*)d_in[4];
    const float* gate = (const float*)d_in[5];
    const float* M    = (const float*)d_in[6];
    const float* z    = (const float*)d_in[7];

    char* ws = (char*)d_ws;
    unsigned short* Wfull = (unsigned short*)(ws + WQKV_OFF);
    unsigned short* Wo_b  = (unsigned short*)(ws + WO_OFF);
    unsigned short* MbT   = (unsigned short*)(ws + MBT_OFF);
    unsigned short* Qb    = (unsigned short*)(ws + QB_OFF);
    unsigned short* Kb    = (unsigned short*)(ws + KB_OFF);
    unsigned short* Vb    = (unsigned short*)(ws + VB_OFF);
    unsigned short* Pb    = (unsigned short*)(ws + PB_OFF);
    unsigned short* AccB  = (unsigned short*)(ws + ACC_OFF);
    float* KV    = (float*)(ws + KV_OFF);
    unsigned short* KVp = (unsigned short*)(ws + KVP_OFF);
    float* Mpart = (float*)(ws + MPART_OFF);
    float* ksum  = (float*)(ws + KSUM_OFF);
    float* kpre  = (float*)(ws + KPRE_OFF);

    float* outp   = (float*)d_out;
    float* out_mz = outp + (size_t)Nrow*Hsz;

    k_cvt_w<<<((4*WN + 16384)/4 + 255)/256, 256, 0, stream>>>(wq, wk, wv, wo, M, Wfull, MbT);
    k_gemm_qkv<<<dim3(Nrow/64, 4), 256, 0, stream>>>(X, Wfull, AccB);
    k_qkv_epi<<<(3*Nrow*16)/256, 256, 0, stream>>>(AccB, Qb, Kb, Vb);
    k_delta_kv<<<dim3(NCH, 4, 2), 256, 0, stream>>>(Kb, Vb, MbT, z, KV, ksum, Mpart);
    k_scan_final<<<194, 256, 0, stream>>>(KV, ksum, M, z, Mpart, KVp, kpre, out_mz);
    k_attn<<<dim3(NCH, 4, 2), 256, 0, stream>>>(Qb, KVp, kpre, MbT, z, gate, Kb, Vb, Pb);
    k_gemm_out<<<dim3(Nrow/128, Hsz/128), 256, 0, stream>>>(Pb, Wo_b, outp);
}